// Round 8
// baseline (400.302 us; speedup 1.0000x reference)
//
#include <hip/hip_runtime.h>
#include <hip/hip_bf16.h>

// NonLocalBlock B=4,C=256,H=W=64 (N=4096) — round 8.
//  wcvt : weights fp32 -> bf16 once
//  qkv  : 32-token tiles, grid 512 (2 blocks/CU)
//  attn : 32q blocks, 512 thr, grid 512 -> 16 waves/CU (occupancy first).
//         4 producer waves (S=KQ^T per 128-key chunk, qf resident=64 VGPR),
//         4 consumer waves (PV, 64-c strip). P via XOR-swizzled 16KB LDS
//         (1 frag = 1 granule, conflict-free b128). 1 barrier/chunk.
//         proj + residual fused in epilogue. All paths <= ~110 VGPR.
// ws = QT | KT | V | Wbf = 25.7 MiB.

typedef __attribute__((ext_vector_type(4))) short s16x4;
typedef __attribute__((ext_vector_type(8))) short s16x8;
typedef __attribute__((ext_vector_type(16))) float f32x16;

#define MFMA32(a, b, c) __builtin_amdgcn_mfma_f32_32x32x16_bf16((a), (b), (c), 0, 0, 0)

constexpr int Cc = 256;
constexpr int Nn = 4096;

__device__ inline short f2bf(float f) {
    unsigned int u = __builtin_bit_cast(unsigned int, f);
    u = (u + 0x7fffu + ((u >> 16) & 1u)) >> 16;   // RNE
    return (short)u;
}

// 32x32x16 bf16 MFMA layouts (verified across r2-r7 passing runs):
//   A[m=lane&31][k=(lane>>5)*8+j]   B[k=(lane>>5)*8+j][n=lane&31]
//   C/D: col=lane&31, row=(r&3)+8*(r>>2)+4*(lane>>5)

// ---------------------------------------------------------------- wcvt
__global__ __launch_bounds__(256, 4) void wcvt_kernel(
    const float* __restrict__ wq, const float* __restrict__ wk,
    const float* __restrict__ wv, const float* __restrict__ wp,
    short* __restrict__ W)
{
    const int m = blockIdx.y;
    const float* src = (m == 0) ? wq : (m == 1) ? wk : (m == 2) ? wv : wp;
    const int idx = (blockIdx.x * 256 + threadIdx.x) * 8;
    float4 a = *(const float4*)(src + idx);
    float4 b = *(const float4*)(src + idx + 4);
    s16x8 p = { f2bf(a.x), f2bf(a.y), f2bf(a.z), f2bf(a.w),
                f2bf(b.x), f2bf(b.y), f2bf(b.z), f2bf(b.w) };
    *(s16x8*)(W + m * 65536 + idx) = p;
}

// ---------------------------------------------------------------- qkv
// 32-token tiles, grid (128 nt, 4 b) = 512 blocks -> 2 blocks/CU.
__global__ __launch_bounds__(256, 2) void qkv_kernel(
    const float* __restrict__ x, const short* __restrict__ W,
    const float* __restrict__ bq, const float* __restrict__ bk,
    const float* __restrict__ bv,
    short* __restrict__ QT, short* __restrict__ KT, short* __restrict__ V)
{
    const int nt = blockIdx.x, b = blockIdx.y;
    const int n0 = nt * 32;
    const int t = threadIdx.x, lane = t & 63, wid = t >> 6, h = lane >> 5, l31 = lane & 31;

    __shared__ alignas(16) short xT[32][264];      // x^T tile [n][c] bf16

    const float* xb = x + (size_t)b * Cc * Nn;
    #pragma unroll
    for (int r = 0; r < 8; ++r) {                  // 32n x 256c transpose+cvt
        int idx = r * 256 + t;
        int n = idx & 31, c = (idx >> 5) * 4;
        float f0 = xb[(size_t)(c + 0) * Nn + n0 + n];
        float f1 = xb[(size_t)(c + 1) * Nn + n0 + n];
        float f2 = xb[(size_t)(c + 2) * Nn + n0 + n];
        float f3 = xb[(size_t)(c + 3) * Nn + n0 + n];
        s16x4 p = { f2bf(f0), f2bf(f1), f2bf(f2), f2bf(f3) };
        *(s16x4*)&xT[n][c] = p;
    }
    __syncthreads();

    // ---- Q,K: D[n][o] (A = xT rows, B = W rows)
    #pragma unroll
    for (int mat = 0; mat < 2; ++mat) {
        const short* Wm = W + mat * 65536;
        const float* bias = (mat == 0) ? bq : bk;
        f32x16 acc[2];
        #pragma unroll
        for (int s = 0; s < 2; ++s)
            #pragma unroll
            for (int r = 0; r < 16; ++r) acc[s][r] = 0.f;
        #pragma unroll 4
        for (int kk = 0; kk < 16; ++kk) {
            s16x8 a = *(const s16x8*)&xT[l31][kk*16 + h*8];
            #pragma unroll
            for (int s = 0; s < 2; ++s) {
                int ot = wid*2 + s;
                s16x8 bb = *(const s16x8*)&Wm[(size_t)(ot*32 + l31) * Cc + kk*16 + h*8];
                acc[s] = MFMA32(a, bb, acc[s]);
            }
        }
        short* dst = ((mat == 0) ? QT : KT) + (size_t)b * Nn * Cc;
        #pragma unroll
        for (int s = 0; s < 2; ++s) {
            int o = (wid*2 + s)*32 + l31;
            float bia = bias[o];
            #pragma unroll
            for (int r = 0; r < 16; ++r) {
                int n = (r & 3) + 8*(r >> 2) + 4*h;
                dst[(size_t)(n0 + n) * Cc + o] = f2bf(acc[s][r] + bia);
            }
        }
    }

    // ---- V: D[o][n] (A = W rows, B = xT rows)
    {
        const short* Wm = W + 2 * 65536;
        f32x16 acc[2];
        #pragma unroll
        for (int s = 0; s < 2; ++s)
            #pragma unroll
            for (int r = 0; r < 16; ++r) acc[s][r] = 0.f;
        #pragma unroll 4
        for (int kk = 0; kk < 16; ++kk) {
            s16x8 bx = *(const s16x8*)&xT[l31][kk*16 + h*8];
            #pragma unroll
            for (int s = 0; s < 2; ++s) {
                int ot = wid*2 + s;
                s16x8 aw = *(const s16x8*)&Wm[(size_t)(ot*32 + l31) * Cc + kk*16 + h*8];
                acc[s] = MFMA32(aw, bx, acc[s]);
            }
        }
        short* dst = V + (size_t)b * Cc * Nn;
        #pragma unroll
        for (int s = 0; s < 2; ++s) {
            #pragma unroll
            for (int r = 0; r < 16; ++r) {
                int o = (wid*2 + s)*32 + (r & 3) + 8*(r >> 2) + 4*h;
                dst[(size_t)o * Nn + n0 + l31] = f2bf(acc[s][r] + bv[o]);
            }
        }
    }
}

// ---------------------------------------------------------------- attn (+proj)
// grid 512, block 512 (8 waves) -> 2 blocks/CU, 16 waves/CU.
// Block = 32-query tile. Chunk = 128 keys, 32 chunks, 1 barrier/chunk.
// Ps: [2][32 i][16 granules(8j)] XOR-swizzled by (i&7): write 8B at
// gran^(i&7); read b128 = one granule -> 8 distinct banks/quad, conflict-free.
__global__ __launch_bounds__(512, 4) void attn_kernel(
    const short* __restrict__ QTg, const short* __restrict__ KTg,
    const short* __restrict__ Vg, const short* __restrict__ W,
    const float* __restrict__ bp, const float* __restrict__ x,
    float* __restrict__ out)
{
    const int bid = blockIdx.x;
    const int b  = (bid & 7) >> 1;               // batch per XCD pair
    const int qt = ((bid >> 3) << 1) | (bid & 1);
    const int i0 = qt * 32;

    const int t = threadIdx.x, lane = t & 63, wid = t >> 6, h = lane >> 5, l31 = lane & 31;

    __shared__ alignas(16) short Ps[2][32 * 128];   // 16 KB, swizzled
    __shared__ alignas(16) short T[32][264];        // O tile [i][c] (epilogue)
    __shared__ float lred[4][32];

    const short* Qb = QTg + (size_t)b * Nn * Cc;
    const short* Kb = KTg + (size_t)b * Nn * Cc;
    const short* Vb = Vg  + (size_t)b * Cc * Nn;

    const float SC = 0.09016844005f;             // C^-0.5 * log2(e)
    const int swz = l31 & 7;

    f32x16 oacc[2];
    #pragma unroll
    for (int s = 0; s < 2; ++s)
        #pragma unroll
        for (int r = 0; r < 16; ++r) oacc[s][r] = 0.f;
    float lacc = 0.f;

    s16x8 qf[16];                                // producer-resident Q (64 VGPR)
    if (wid < 4) {
        const short* qrow = Qb + (size_t)(i0 + l31) * Cc + h*8;
        #pragma unroll
        for (int kc = 0; kc < 16; ++kc) qf[kc] = *(const s16x8*)(qrow + kc*16);
    }

    for (int tt = 0; tt <= 32; ++tt) {
        if (wid < 4) {
            if (tt < 32) {                       // produce chunk tt
                const int cb = tt & 1;
                const short* krow = Kb + (size_t)(tt*128 + wid*32 + l31) * Cc + h*8;
                f32x16 s;
                #pragma unroll
                for (int r = 0; r < 16; ++r) s[r] = 0.f;
                #pragma unroll
                for (int kc = 0; kc < 16; ++kc)
                    s = MFMA32(*(const s16x8*)(krow + kc*16), qf[kc], s);
                short* pbase = &Ps[cb][l31 * 128];
                #pragma unroll
                for (int g = 0; g < 4; ++g) {
                    float e0 = exp2f(s[4*g+0] * SC);
                    float e1 = exp2f(s[4*g+1] * SC);
                    float e2 = exp2f(s[4*g+2] * SC);
                    float e3 = exp2f(s[4*g+3] * SC);
                    lacc += (e0 + e1) + (e2 + e3);
                    s16x4 pk = { f2bf(e0), f2bf(e1), f2bf(e2), f2bf(e3) };
                    *(s16x4*)&pbase[((wid*4 + g) ^ swz) * 8 + 4*h] = pk;
                }
            }
        } else {
            if (tt >= 1) {                       // consume chunk tt-1
                const int jt = tt - 1, pb = jt & 1, j0 = jt * 128;
                const int cbase = (wid - 4) * 64;
                const short* v0 = Vb + (size_t)(cbase +  0 + l31) * Nn + j0 + h*8;
                const short* v1 = Vb + (size_t)(cbase + 32 + l31) * Nn + j0 + h*8;
                const short* pbase = &Ps[pb][l31 * 128];
                #pragma unroll
                for (int ks = 0; ks < 8; ++ks) {
                    s16x8 p  = *(const s16x8*)&pbase[((2*ks + h) ^ swz) * 8];
                    oacc[0] = MFMA32(*(const s16x8*)(v0 + ks*16), p, oacc[0]);
                    oacc[1] = MFMA32(*(const s16x8*)(v1 + ks*16), p, oacc[1]);
                }
            }
        }
        __syncthreads();
    }

    // ---- softmax denominators (4 producer strips)
    lacc += __shfl_xor(lacc, 32);
    if (wid < 4 && h == 0) lred[wid][l31] = lacc;
    __syncthreads();
    const float linv = 1.0f / (lred[0][l31] + lred[1][l31] + lred[2][l31] + lred[3][l31]);

    // ---- consumers: normalize O into T [i][c]
    if (wid >= 4) {
        const int cbase = (wid - 4) * 64;
        #pragma unroll
        for (int ct = 0; ct < 2; ++ct) {
            #pragma unroll
            for (int g = 0; g < 4; ++g) {
                s16x4 pk = { f2bf(oacc[ct][4*g+0] * linv), f2bf(oacc[ct][4*g+1] * linv),
                             f2bf(oacc[ct][4*g+2] * linv), f2bf(oacc[ct][4*g+3] * linv) };
                *(s16x4*)&T[l31][cbase + ct*32 + g*8 + 4*h] = pk;
            }
        }
    }
    __syncthreads();

    // ---- fused projection + residual (all 8 waves, o-strip 32 each)
    const short* Wp = W + 3 * 65536;
    f32x16 pacc;
    #pragma unroll
    for (int r = 0; r < 16; ++r) pacc[r] = 0.f;
    const short* wrow = Wp + (size_t)(wid*32 + l31) * Cc + h*8;
    #pragma unroll
    for (int kc = 0; kc < 16; ++kc) {
        s16x8 wa = *(const s16x8*)(wrow + kc*16);
        s16x8 tb = *(const s16x8*)&T[l31][kc*16 + h*8];
        pacc = MFMA32(wa, tb, pacc);
    }
    const float* xb = x + (size_t)b * Cc * Nn;
    float* ob = out + (size_t)b * Cc * Nn;
    #pragma unroll
    for (int r = 0; r < 16; ++r) {
        int o = wid*32 + (r & 3) + 8*(r >> 2) + 4*h;
        size_t idx = (size_t)o * Nn + i0 + l31;
        ob[idx] = xb[idx] + pacc[r] + bp[o];
    }
}

// ---------------------------------------------------------------- launch
extern "C" void kernel_launch(void* const* d_in, const int* in_sizes, int n_in,
                              void* d_out, int out_size, void* d_ws, size_t ws_size,
                              hipStream_t stream)
{
    const float* x  = (const float*)d_in[0];
    const float* wq = (const float*)d_in[1];
    const float* bq = (const float*)d_in[2];
    const float* wk = (const float*)d_in[3];
    const float* bk = (const float*)d_in[4];
    const float* wv = (const float*)d_in[5];
    const float* bv = (const float*)d_in[6];
    const float* wp = (const float*)d_in[7];
    const float* bp = (const float*)d_in[8];

    const size_t elems = (size_t)4 * Nn * Cc;                 // 4.19 M / buffer
    const size_t need  = (3 * elems + 4 * 65536) * sizeof(short);  // 25.7 MiB
    if (ws_size < need) return;
    short* QT  = (short*)d_ws;                 // [b][n][c] bf16
    short* KT  = QT + elems;                   // [b][n][c] bf16
    short* V   = KT + elems;                   // [b][c][n] bf16
    short* Wbf = V + elems;                    // 4 x [o][c] bf16
    (void)in_sizes; (void)n_in; (void)out_size;

    wcvt_kernel<<<dim3(32, 4), 256, 0, stream>>>(wq, wk, wv, wp, Wbf);
    qkv_kernel<<<dim3(128, 4), 256, 0, stream>>>(x, Wbf, bq, bk, bv, QT, KT, V);
    attn_kernel<<<dim3(512), 512, 0, stream>>>(QT, KT, V, Wbf, bp, x, (float*)d_out);
}

// Round 9
// 344.154 us; speedup vs baseline: 1.1631x; 1.1631x over previous
//
#include <hip/hip_runtime.h>
#include <hip/hip_bf16.h>

// NonLocalBlock B=4,C=256,H=W=64 (N=4096) — round 9.
//  wcvt : weights fp32 -> bf16 once
//  qkv  : 64-token x single-mat blocks, grid 768 (3 blocks/CU, 12 waves/CU)
//  attn : r3-lineage wave-specialized flash, 768 thr (12 waves/CU, 3/SIMD):
//         4 producers (32j x 32i S-tile/step, K frags DIRECT from L2, qf
//         resident), 8 consumers (32c strip, V direct from L2). LDS only for
//         P handoff (17 KB dbuf, [i][68] = 2-way-free banks). 1 barrier/step.
//         proj + residual fused in epilogue. All paths <= ~150 VGPR (LB 768,3).
// ws = QT | KT | V | Wbf = 25.7 MiB.

typedef __attribute__((ext_vector_type(4))) short s16x4;
typedef __attribute__((ext_vector_type(8))) short s16x8;
typedef __attribute__((ext_vector_type(16))) float f32x16;

#define MFMA32(a, b, c) __builtin_amdgcn_mfma_f32_32x32x16_bf16((a), (b), (c), 0, 0, 0)

constexpr int Cc = 256;
constexpr int Nn = 4096;

__device__ inline short f2bf(float f) {
    unsigned int u = __builtin_bit_cast(unsigned int, f);
    u = (u + 0x7fffu + ((u >> 16) & 1u)) >> 16;   // RNE
    return (short)u;
}

// 32x32x16 bf16 MFMA layouts (verified across r2-r8 passing runs):
//   A[m=lane&31][k=(lane>>5)*8+j]   B[k=(lane>>5)*8+j][n=lane&31]
//   C/D: col=lane&31, row=(r&3)+8*(r>>2)+4*(lane>>5)

// ---------------------------------------------------------------- wcvt
__global__ __launch_bounds__(256, 4) void wcvt_kernel(
    const float* __restrict__ wq, const float* __restrict__ wk,
    const float* __restrict__ wv, const float* __restrict__ wp,
    short* __restrict__ W)
{
    const int m = blockIdx.y;
    const float* src = (m == 0) ? wq : (m == 1) ? wk : (m == 2) ? wv : wp;
    const int idx = (blockIdx.x * 256 + threadIdx.x) * 8;
    float4 a = *(const float4*)(src + idx);
    float4 b = *(const float4*)(src + idx + 4);
    s16x8 p = { f2bf(a.x), f2bf(a.y), f2bf(a.z), f2bf(a.w),
                f2bf(b.x), f2bf(b.y), f2bf(b.z), f2bf(b.w) };
    *(s16x8*)(W + m * 65536 + idx) = p;
}

// ---------------------------------------------------------------- qkv
// 64-token x single-mat blocks, grid (64 nt, 4 b, 3 mat) = 768 -> 3 blocks/CU.
__global__ __launch_bounds__(256, 3) void qkv_kernel(
    const float* __restrict__ x, const short* __restrict__ W,
    const float* __restrict__ bq, const float* __restrict__ bk,
    const float* __restrict__ bv,
    short* __restrict__ QT, short* __restrict__ KT, short* __restrict__ V)
{
    const int nt = blockIdx.x, b = blockIdx.y, mat = blockIdx.z;
    const int n0 = nt * 64;
    const short* Wm = W + mat * 65536;
    const float* bias = (mat == 0) ? bq : (mat == 1) ? bk : bv;
    const int t = threadIdx.x, lane = t & 63, wid = t >> 6, h = lane >> 5, l31 = lane & 31;

    __shared__ alignas(16) short xT[64][264];      // x^T tile [n][c] bf16

    const float* xb = x + (size_t)b * Cc * Nn;
    #pragma unroll
    for (int r = 0; r < 16; ++r) {                 // transpose+cvt 64n x 256c
        int g = r * 256 + t;
        int n = g & 63, cg = g >> 6;
        float f0 = xb[(size_t)(4*cg + 0) * Nn + n0 + n];
        float f1 = xb[(size_t)(4*cg + 1) * Nn + n0 + n];
        float f2 = xb[(size_t)(4*cg + 2) * Nn + n0 + n];
        float f3 = xb[(size_t)(4*cg + 3) * Nn + n0 + n];
        s16x4 p = { f2bf(f0), f2bf(f1), f2bf(f2), f2bf(f3) };
        *(s16x4*)&xT[n][4*cg] = p;
    }
    __syncthreads();

    f32x16 acc[4];
    #pragma unroll
    for (int s = 0; s < 4; ++s)
        #pragma unroll
        for (int r = 0; r < 16; ++r) acc[s][r] = 0.f;

    if (mat < 2) {
        // D[n][o] = sum_c xT[n][c] w[o][c]   (A = xT LDS, B = W rows from L2)
        const int mw = wid & 1, nwb = (wid >> 1) * 4;
        #pragma unroll 4
        for (int kk = 0; kk < 16; ++kk) {
            s16x8 a = *(const s16x8*)&xT[mw*32 + l31][kk*16 + h*8];
            #pragma unroll
            for (int s = 0; s < 4; ++s) {
                s16x8 bb = *(const s16x8*)&Wm[(size_t)((nwb + s)*32 + l31) * Cc + kk*16 + h*8];
                acc[s] = MFMA32(a, bb, acc[s]);
            }
        }
        short* dst = ((mat == 0) ? QT : KT) + (size_t)b * Nn * Cc;
        #pragma unroll
        for (int s = 0; s < 4; ++s) {
            int o = (nwb + s)*32 + l31;
            float bia = bias[o];
            #pragma unroll
            for (int r = 0; r < 16; ++r) {
                int n = mw*32 + (r & 3) + 8*(r >> 2) + 4*h;
                dst[(size_t)(n0 + n) * Cc + o] = f2bf(acc[s][r] + bia);
            }
        }
    } else {
        // D[o][n] = sum_c w[o][c] xT[n][c]   (A = W rows, B = xT LDS)
        #pragma unroll 4
        for (int kk = 0; kk < 16; ++kk) {
            s16x8 a0 = *(const s16x8*)&Wm[(size_t)((wid*2 + 0)*32 + l31) * Cc + kk*16 + h*8];
            s16x8 a1 = *(const s16x8*)&Wm[(size_t)((wid*2 + 1)*32 + l31) * Cc + kk*16 + h*8];
            s16x8 b0 = *(const s16x8*)&xT[ 0 + l31][kk*16 + h*8];
            s16x8 b1 = *(const s16x8*)&xT[32 + l31][kk*16 + h*8];
            acc[0] = MFMA32(a0, b0, acc[0]);
            acc[1] = MFMA32(a0, b1, acc[1]);
            acc[2] = MFMA32(a1, b0, acc[2]);
            acc[3] = MFMA32(a1, b1, acc[3]);
        }
        short* dst = V + (size_t)b * Cc * Nn;
        #pragma unroll
        for (int sub = 0; sub < 4; ++sub) {
            int mc = sub >> 1, nc = sub & 1;
            int nloc = nc*32 + l31;
            #pragma unroll
            for (int r = 0; r < 16; ++r) {
                int o = (wid*2 + mc)*32 + (r & 3) + 8*(r >> 2) + 4*h;
                dst[(size_t)o * Nn + n0 + nloc] = f2bf(acc[sub][r] + bias[o]);
            }
        }
    }
}

// ---------------------------------------------------------------- attn (+proj)
// grid 256, block 768 (12 waves) -> 1 block/CU, 3 waves/SIMD.
// Waves 0-3: producers (mj=w>>1, ni=w&1): per 64-key step one 32jx32i S-tile,
//   K frags from L2, exp, P -> LDS [i][68] dbuf. Waves 4-11: consumers, 32-c
//   strip each, V frags from L2, PV accumulate. 1 barrier/step.
__global__ __launch_bounds__(768, 3) void attn_kernel(
    const short* __restrict__ QTg, const short* __restrict__ KTg,
    const short* __restrict__ Vg, const short* __restrict__ W,
    const float* __restrict__ bp, const float* __restrict__ x,
    float* __restrict__ out)
{
    const int bid = blockIdx.x;
    const int b  = (bid & 7) >> 1;               // batch per XCD pair
    const int qt = ((bid >> 3) << 1) | (bid & 1);
    const int i0 = qt * 64;

    const int t = threadIdx.x, lane = t & 63, wid = t >> 6, h = lane >> 5, l31 = lane & 31;

    __shared__ alignas(16) short Ps[2][64][68];  // P dbuf [i][j], 2-way-free banks
    __shared__ alignas(16) short T[64][264];     // O tile [i][c] (epilogue)
    __shared__ float lred[4][32];

    const short* Qb = QTg + (size_t)b * Nn * Cc;
    const short* Kb = KTg + (size_t)b * Nn * Cc;
    const short* Vb = Vg  + (size_t)b * Cc * Nn;

    const float SC = 0.09016844005f;             // C^-0.5 * log2(e)

    f32x16 oacc[2];
    #pragma unroll
    for (int s = 0; s < 2; ++s)
        #pragma unroll
        for (int r = 0; r < 16; ++r) oacc[s][r] = 0.f;
    float lacc = 0.f;

    s16x8 qf[16];                                // producer-resident Q (64 VGPR)
    const int mj = wid >> 1, ni = wid & 1;       // producer role (wid<4)
    if (wid < 4) {
        const short* qrow = Qb + (size_t)(i0 + ni*32 + l31) * Cc + h*8;
        #pragma unroll
        for (int kc = 0; kc < 16; ++kc) qf[kc] = *(const s16x8*)(qrow + kc*16);
    }

    for (int tt = 0; tt <= 64; ++tt) {
        if (wid < 4) {
            if (tt < 64) {                       // produce chunk tt
                const int cb = tt & 1;
                const short* krow = Kb + (size_t)(tt*64 + mj*32 + l31) * Cc + h*8;
                f32x16 s0, s1;
                #pragma unroll
                for (int r = 0; r < 16; ++r) { s0[r] = 0.f; s1[r] = 0.f; }
                #pragma unroll
                for (int ph = 0; ph < 2; ++ph) { // 2 phases: cap live K frags
                    s16x8 kf[8];
                    #pragma unroll
                    for (int q = 0; q < 8; ++q)
                        kf[q] = *(const s16x8*)(krow + (ph*8 + q)*16);
                    #pragma unroll
                    for (int q = 0; q < 8; q += 2) {
                        s0 = MFMA32(kf[q],     qf[ph*8 + q],     s0);
                        s1 = MFMA32(kf[q + 1], qf[ph*8 + q + 1], s1);
                    }
                }
                const int ip = ni*32 + l31;
                #pragma unroll
                for (int g = 0; g < 4; ++g) {
                    float e0 = exp2f((s0[4*g+0] + s1[4*g+0]) * SC);
                    float e1 = exp2f((s0[4*g+1] + s1[4*g+1]) * SC);
                    float e2 = exp2f((s0[4*g+2] + s1[4*g+2]) * SC);
                    float e3 = exp2f((s0[4*g+3] + s1[4*g+3]) * SC);
                    lacc += (e0 + e1) + (e2 + e3);
                    s16x4 pk = { f2bf(e0), f2bf(e1), f2bf(e2), f2bf(e3) };
                    *(s16x4*)&Ps[cb][ip][mj*32 + g*8 + 4*h] = pk;
                }
            }
        } else {
            if (tt >= 1) {                       // consume chunk tt-1
                const int jt = tt - 1, pb = jt & 1, j0 = jt * 64;
                const int cbase = (wid - 4) * 32;
                const short* vrow = Vb + (size_t)(cbase + l31) * Nn + j0 + h*8;
                s16x8 vf[4], p0[4], p1[4];
                #pragma unroll
                for (int ks = 0; ks < 4; ++ks) {
                    vf[ks] = *(const s16x8*)(vrow + ks*16);
                    p0[ks] = *(const s16x8*)&Ps[pb][ 0 + l31][ks*16 + h*8];
                    p1[ks] = *(const s16x8*)&Ps[pb][32 + l31][ks*16 + h*8];
                }
                #pragma unroll
                for (int ks = 0; ks < 4; ++ks) {
                    oacc[0] = MFMA32(vf[ks], p0[ks], oacc[0]);
                    oacc[1] = MFMA32(vf[ks], p1[ks], oacc[1]);
                }
            }
        }
        __syncthreads();
    }

    // ---- softmax denominators: lred[w] = partial for i-strip (w&1), j-half (w>>1)
    lacc += __shfl_xor(lacc, 32);
    if (wid < 4 && h == 0) lred[wid][l31] = lacc;
    __syncthreads();

    // ---- consumers: normalize O into T [i][c]
    if (wid >= 4) {
        const int cbase = (wid - 4) * 32;
        const float linv0 = 1.0f / (lred[0][l31] + lred[2][l31]);  // i-tile 0
        const float linv1 = 1.0f / (lred[1][l31] + lred[3][l31]);  // i-tile 1
        #pragma unroll
        for (int it = 0; it < 2; ++it) {
            const float lv = it ? linv1 : linv0;
            const int ip = it*32 + l31;
            #pragma unroll
            for (int g = 0; g < 4; ++g) {
                s16x4 pk = { f2bf(oacc[it][4*g+0] * lv), f2bf(oacc[it][4*g+1] * lv),
                             f2bf(oacc[it][4*g+2] * lv), f2bf(oacc[it][4*g+3] * lv) };
                *(s16x4*)&T[ip][cbase + g*8 + 4*h] = pk;
            }
        }
    }
    __syncthreads();

    // ---- fused projection + residual (waves 0-7, o-strip 32 each)
    if (wid < 8) {
        const short* Wp = W + 3 * 65536;
        f32x16 pacc[2];
        #pragma unroll
        for (int s = 0; s < 2; ++s)
            #pragma unroll
            for (int r = 0; r < 16; ++r) pacc[s][r] = 0.f;
        const short* wrow = Wp + (size_t)(wid*32 + l31) * Cc + h*8;
        #pragma unroll 4
        for (int kc = 0; kc < 16; ++kc) {
            s16x8 wa = *(const s16x8*)(wrow + kc*16);
            s16x8 b0 = *(const s16x8*)&T[ 0 + l31][kc*16 + h*8];
            s16x8 b1 = *(const s16x8*)&T[32 + l31][kc*16 + h*8];
            pacc[0] = MFMA32(wa, b0, pacc[0]);
            pacc[1] = MFMA32(wa, b1, pacc[1]);
        }
        const float* xb = x + (size_t)b * Cc * Nn;
        float* ob = out + (size_t)b * Cc * Nn;
        #pragma unroll
        for (int it = 0; it < 2; ++it) {
            int iloc = i0 + it*32 + l31;
            #pragma unroll
            for (int r = 0; r < 16; ++r) {
                int o = wid*32 + (r & 3) + 8*(r >> 2) + 4*h;
                size_t idx = (size_t)o * Nn + iloc;
                ob[idx] = xb[idx] + pacc[it][r] + bp[o];
            }
        }
    }
}

// ---------------------------------------------------------------- launch
extern "C" void kernel_launch(void* const* d_in, const int* in_sizes, int n_in,
                              void* d_out, int out_size, void* d_ws, size_t ws_size,
                              hipStream_t stream)
{
    const float* x  = (const float*)d_in[0];
    const float* wq = (const float*)d_in[1];
    const float* bq = (const float*)d_in[2];
    const float* wk = (const float*)d_in[3];
    const float* bk = (const float*)d_in[4];
    const float* wv = (const float*)d_in[5];
    const float* bv = (const float*)d_in[6];
    const float* wp = (const float*)d_in[7];
    const float* bp = (const float*)d_in[8];

    const size_t elems = (size_t)4 * Nn * Cc;                 // 4.19 M / buffer
    const size_t need  = (3 * elems + 4 * 65536) * sizeof(short);  // 25.7 MiB
    if (ws_size < need) return;
    short* QT  = (short*)d_ws;                 // [b][n][c] bf16
    short* KT  = QT + elems;                   // [b][n][c] bf16
    short* V   = KT + elems;                   // [b][c][n] bf16
    short* Wbf = V + elems;                    // 4 x [o][c] bf16
    (void)in_sizes; (void)n_in; (void)out_size;

    wcvt_kernel<<<dim3(32, 4), 256, 0, stream>>>(wq, wk, wv, wp, Wbf);
    qkv_kernel<<<dim3(64, 4, 3), 256, 0, stream>>>(x, Wbf, bq, bk, bv, QT, KT, V);
    attn_kernel<<<dim3(256), 768, 0, stream>>>(QT, KT, V, Wbf, bp, x, (float*)d_out);
}